// Round 1
// baseline (10900.666 us; speedup 1.0000x reference)
//
#include <hip/hip_runtime.h>
#include <stdint.h>

// LSTM_34359738368754: 2-layer LSTM, T=180 B=512 H=1024 I=V=108.
// Strategy:
//  - W_comb = W_ih2 @ W_mid precomputed (mid-Linear folded into cell-2 GEMM).
//  - Gate-interleaved weight rows n' = 4*(n%1024) + gate  ->  cell update is
//    block-local in the GEMM epilogue (i,f,g,o adjacent in the N tile).
//  - Per step: 2 kernels (cell1 GEMM+update, cell2 GEMM+update). 360 launches.
//  - GEMM: 64x128 block tile, BK=64, global_load_lds(16B), mfma 16x16x32 bf16,
//    grid (32,8)=256 blocks. fp32 cell state; bf16 GEMM operands.
//  - c2 stored bf16 per step; one batched final GEMM + fused log_softmax.

typedef unsigned short u16;
typedef __attribute__((ext_vector_type(4))) float f32x4;
typedef __attribute__((ext_vector_type(8))) short bf16x8;

#define HDIM 1024
#define BSZ  512
#define TSTEPS 180
#define IIN  108
#define VOUT 108

__device__ __forceinline__ u16 f2bf(float x) {
  union { float f; unsigned u; } v; v.f = x;
  unsigned r = (v.u + 0x7fffu + ((v.u >> 16) & 1u)) >> 16;  // RNE
  return (u16)r;
}
__device__ __forceinline__ float sigm(float x) { return 1.f / (1.f + __expf(-x)); }
__device__ __forceinline__ float tanh_(float x) {
  float a = fabsf(x), t = __expf(-2.f * a);
  float r = (1.f - t) / (1.f + t);
  return x < 0.f ? -r : r;
}
// gate-interleave permutation of the 4H dimension
__device__ __forceinline__ int permrow(int n) { return ((n & 1023) << 2) | (n >> 10); }

__device__ __forceinline__ void load16_lds(const void* g, void* l) {
  __builtin_amdgcn_global_load_lds(
      (const __attribute__((address_space(1))) unsigned int*)g,
      (__attribute__((address_space(3))) unsigned int*)l, 16, 0, 0);
}

// C(64x128) at (m0,n0) = sum_s A_s @ B_s^T ; A_s:[M][K_s] bf16 rm, B_s:[N][K_s] bf16 rm.
__device__ __forceinline__ void gemm_tile_64x128(
    f32x4 acc[2][4],
    const u16* A0, const u16* B0, int K0,
    const u16* A1, const u16* B1, int K1,
    int m0, int n0, u16* As, u16* Bs)
{
  const int tid  = threadIdx.x;
  const int lane = tid & 63;
  const int wave = tid >> 6;
  const int quad = lane >> 4;
  const int l16  = lane & 15;
  const int wm   = wave >> 1;   // 2x2 wave grid, wave tile 32x64
  const int wn   = wave & 1;

#pragma unroll
  for (int mt = 0; mt < 2; ++mt)
#pragma unroll
    for (int nt = 0; nt < 4; ++nt) {
      f32x4 z = {0.f, 0.f, 0.f, 0.f};
      acc[mt][nt] = z;
    }

  for (int s = 0; s < 2; ++s) {
    const u16* A = s ? A1 : A0;
    const u16* B = s ? B1 : B0;
    const int  K = s ? K1 : K0;
    for (int k0 = 0; k0 < K; k0 += 64) {
      __syncthreads();                       // protect LDS from prior readers
      // A tile: 64x64 bf16 = 512 16B-chunks; 2 issues/wave
#pragma unroll
      for (int i = 0; i < 2; ++i) {
        int chunk = (wave * 2 + i) * 64 + lane;
        const u16* g = A + (size_t)(m0 + (chunk >> 3)) * K + k0 + ((chunk & 7) << 3);
        load16_lds(g, As + (wave * 2 + i) * 512);
      }
      // B tile: 128x64 bf16 = 1024 chunks; 4 issues/wave
#pragma unroll
      for (int i = 0; i < 4; ++i) {
        int chunk = (wave * 4 + i) * 64 + lane;
        const u16* g = B + (size_t)(n0 + (chunk >> 3)) * K + k0 + ((chunk & 7) << 3);
        load16_lds(g, Bs + (wave * 4 + i) * 512);
      }
      __syncthreads();                       // barrier drains vmcnt
      const bf16x8* Av = (const bf16x8*)As;
      const bf16x8* Bv = (const bf16x8*)Bs;
#pragma unroll
      for (int kk = 0; kk < 2; ++kk) {
        bf16x8 a[2], b[4];
#pragma unroll
        for (int mt = 0; mt < 2; ++mt)
          a[mt] = Av[(wm * 32 + mt * 16 + l16) * 8 + kk * 4 + quad];
#pragma unroll
        for (int nt = 0; nt < 4; ++nt)
          b[nt] = Bv[(wn * 64 + nt * 16 + l16) * 8 + kk * 4 + quad];
#pragma unroll
        for (int mt = 0; mt < 2; ++mt)
#pragma unroll
          for (int nt = 0; nt < 4; ++nt)
            acc[mt][nt] = __builtin_amdgcn_mfma_f32_16x16x32_bf16(
                a[mt], b[nt], acc[mt][nt], 0, 0, 0);
      }
    }
  }
  __syncthreads();                           // LDS free for epilogue reuse
}

// One LSTM cell: gates = A0@B0^T + A1@B1^T + bsum (gate-interleaved N),
// then c' = sig(f)*c + sig(i)*tanh(g); h = sig(o)*tanh(c').
__global__ __launch_bounds__(256, 2) void lstm_step(
    const u16* __restrict__ A0, const u16* __restrict__ B0, int K0,
    const u16* __restrict__ A1, const u16* __restrict__ B1, int K1,
    const float* __restrict__ bsum, float* __restrict__ cState,
    u16* __restrict__ hOut, u16* __restrict__ cOut)
{
  __shared__ __align__(16) char smem[64 * 132 * 4];
  u16* As = (u16*)smem;             // 8 KB
  u16* Bs = (u16*)(smem + 8192);    // 16 KB
  float* gl = (float*)smem;         // reused: gates [64][132] fp32

  const int m0 = blockIdx.y * 64;
  const int n0 = blockIdx.x * 128;
  f32x4 acc[2][4];
  gemm_tile_64x128(acc, A0, B0, K0, A1, B1, K1, m0, n0, As, Bs);

  const int tid  = threadIdx.x;
  const int lane = tid & 63;
  const int wave = tid >> 6;
  const int quad = lane >> 4;
  const int l16  = lane & 15;
  const int wm   = wave >> 1;
  const int wn   = wave & 1;

#pragma unroll
  for (int nt = 0; nt < 4; ++nt) {
    int coll = wn * 64 + nt * 16 + l16;
    float bias = bsum[n0 + coll];
#pragma unroll
    for (int mt = 0; mt < 2; ++mt) {
      int rowb = wm * 32 + mt * 16 + quad * 4;
#pragma unroll
      for (int r = 0; r < 4; ++r)
        gl[(rowb + r) * 132 + coll] = acc[mt][nt][r] + bias;
    }
  }
  __syncthreads();

  const int jbase = blockIdx.x * 32;
#pragma unroll
  for (int it = 0; it < 8; ++it) {
    int idx = it * 256 + tid;       // 64 rows x 32 j
    int m = idx >> 5, jl = idx & 31;
    const f32x4 g4 = *(const f32x4*)(gl + m * 132 + jl * 4);
    float ii = sigm(g4[0]), ff = sigm(g4[1]);
    float gg = tanh_(g4[2]), oo = sigm(g4[3]);
    size_t off = (size_t)(m0 + m) * HDIM + (jbase + jl);
    float cp = cState[off];
    float cn = ff * cp + ii * gg;
    float hh = oo * tanh_(cn);
    cState[off] = cn;
    hOut[off] = f2bf(hh);
    cOut[off] = f2bf(cn);
  }
}

// W_comb = Wih2 @ Wmid (via Bt = Wmid^T), stored bf16 with permuted rows.
__global__ __launch_bounds__(256, 2) void wcomb_gemm(
    const u16* __restrict__ A, const u16* __restrict__ Bt, u16* __restrict__ outp)
{
  __shared__ __align__(16) char smem[24576];
  u16* As = (u16*)smem;
  u16* Bs = (u16*)(smem + 8192);
  const int m0 = blockIdx.y * 64;
  const int n0 = blockIdx.x * 128;
  f32x4 acc[2][4];
  gemm_tile_64x128(acc, A, Bt, 1024, nullptr, nullptr, 0, m0, n0, As, Bs);
  const int lane = threadIdx.x & 63;
  const int wave = threadIdx.x >> 6;
  const int quad = lane >> 4, l16 = lane & 15;
  const int wm = wave >> 1, wn = wave & 1;
#pragma unroll
  for (int mt = 0; mt < 2; ++mt)
#pragma unroll
    for (int nt = 0; nt < 4; ++nt)
#pragma unroll
      for (int r = 0; r < 4; ++r) {
        int mr = m0 + wm * 32 + mt * 16 + quad * 4 + r;
        int c  = n0 + wn * 64 + nt * 16 + l16;
        outp[(size_t)permrow(mr) * 1024 + c] = f2bf(acc[mt][nt][r]);
      }
}

// logits = C2@Wf^T + b  (N tile 128 covers V=108), fused log_softmax, fp32 out.
__global__ __launch_bounds__(256, 2) void final_logsoftmax(
    const u16* __restrict__ C2, const u16* __restrict__ Wf,
    const float* __restrict__ bfin, float* __restrict__ out)
{
  __shared__ __align__(16) char smem[64 * 132 * 4 + 256];
  u16* As = (u16*)smem;
  u16* Bs = (u16*)(smem + 8192);
  float* gl  = (float*)smem;                 // [64][132]
  float* lse = (float*)(smem + 64 * 132 * 4);

  const int m0 = blockIdx.y * 64;
  f32x4 acc[2][4];
  gemm_tile_64x128(acc, C2, Wf, 1024, nullptr, nullptr, 0, m0, 0, As, Bs);

  const int tid = threadIdx.x;
  const int lane = tid & 63;
  const int wave = tid >> 6;
  const int quad = lane >> 4, l16 = lane & 15;
  const int wm = wave >> 1, wn = wave & 1;
#pragma unroll
  for (int nt = 0; nt < 4; ++nt) {
    int coll = wn * 64 + nt * 16 + l16;
    float bias = (coll < VOUT) ? bfin[coll] : 0.f;
#pragma unroll
    for (int mt = 0; mt < 2; ++mt) {
      int rowb = wm * 32 + mt * 16 + quad * 4;
#pragma unroll
      for (int r = 0; r < 4; ++r)
        gl[(rowb + r) * 132 + coll] = acc[mt][nt][r] + bias;
    }
  }
  __syncthreads();
  if (tid < 64) {
    const float* row = gl + tid * 132;
    float mx = -1e30f;
    for (int c = 0; c < VOUT; ++c) mx = fmaxf(mx, row[c]);
    float s = 0.f;
    for (int c = 0; c < VOUT; ++c) s += __expf(row[c] - mx);
    lse[tid] = mx + __logf(s);
  }
  __syncthreads();
  for (int idx = tid; idx < 64 * VOUT; idx += 256) {
    int m = idx / VOUT, c = idx - m * VOUT;
    out[(size_t)(m0 + m) * VOUT + c] = gl[m * 132 + c] - lse[m];
  }
}

// ---------------- setup kernels (fp32 -> bf16, permute, pad) ----------------
__global__ void k_build_w1a(const float* __restrict__ w, u16* __restrict__ d) {
  int idx = blockIdx.x * 256 + threadIdx.x;          // 4096*128
  int n = idx >> 7, k = idx & 127;
  float v = (k < IIN) ? w[n * IIN + k] : 0.f;
  d[permrow(n) * 128 + k] = f2bf(v);
}
__global__ void k_conv_perm1024(const float* __restrict__ w, u16* __restrict__ d) {
  int idx = blockIdx.x * 256 + threadIdx.x;          // 4096*1024
  int n = idx >> 10, k = idx & 1023;
  d[(size_t)permrow(n) * 1024 + k] = f2bf(w[idx]);
}
__global__ void k_conv(const float* __restrict__ s, u16* __restrict__ d) {
  int idx = blockIdx.x * 256 + threadIdx.x;
  d[idx] = f2bf(s[idx]);
}
__global__ void k_transpose1024(const float* __restrict__ s, u16* __restrict__ d) {
  int idx = blockIdx.x * 256 + threadIdx.x;          // 1024*1024
  int r = idx >> 10, c = idx & 1023;
  d[c * 1024 + r] = f2bf(s[idx]);                    // d = s^T
}
__global__ void k_build_wfin(const float* __restrict__ w, u16* __restrict__ d) {
  int idx = blockIdx.x * 256 + threadIdx.x;          // 128*1024
  int r = idx >> 10, c = idx & 1023;
  d[idx] = (r < VOUT) ? f2bf(w[r * 1024 + c]) : (u16)0;
}
__global__ void k_build_xpad(const float* __restrict__ x, u16* __restrict__ d) {
  int idx = blockIdx.x * 256 + threadIdx.x;          // 92160*128
  int row = idx >> 7, k = idx & 127;
  d[idx] = (k < IIN) ? f2bf(x[row * IIN + k]) : (u16)0;
}
__global__ void k_b1sum(const float* __restrict__ a, const float* __restrict__ b,
                        float* __restrict__ d) {
  int n = blockIdx.x * 256 + threadIdx.x;            // 4096
  d[permrow(n)] = a[n] + b[n];
}
__global__ void k_b2sum(const float* __restrict__ Wih2, const float* __restrict__ bmid,
                        const float* __restrict__ bih2, const float* __restrict__ bhh2,
                        float* __restrict__ d) {
  int row = blockIdx.x * 4 + (threadIdx.x >> 6);     // 4096 rows, wave/row
  int lane = threadIdx.x & 63;
  const float* wr = Wih2 + (size_t)row * 1024;
  float s = 0.f;
  for (int k = lane; k < 1024; k += 64) s += wr[k] * bmid[k];
#pragma unroll
  for (int o = 32; o > 0; o >>= 1) s += __shfl_down(s, o);
  if (lane == 0) d[permrow(row)] = s + bih2[row] + bhh2[row];
}

extern "C" void kernel_launch(void* const* d_in, const int* in_sizes, int n_in,
                              void* d_out, int out_size, void* d_ws, size_t ws_size,
                              hipStream_t stream) {
  const float* x    = (const float*)d_in[0];
  const float* Wih1 = (const float*)d_in[1];
  const float* Whh1 = (const float*)d_in[2];
  const float* bih1 = (const float*)d_in[3];
  const float* bhh1 = (const float*)d_in[4];
  const float* Wmid = (const float*)d_in[5];
  const float* bmid = (const float*)d_in[6];
  const float* Wih2 = (const float*)d_in[7];
  const float* Whh2 = (const float*)d_in[8];
  const float* bih2 = (const float*)d_in[9];
  const float* bhh2 = (const float*)d_in[10];
  const float* Wfin = (const float*)d_in[11];
  const float* bfin = (const float*)d_in[12];

  const size_t SZ_XBF = (size_t)TSTEPS * BSZ * 128 * 2;
  const size_t SZ_W1A = (size_t)4096 * 128 * 2;
  const size_t SZ_W1K = (size_t)4096 * 1024 * 2;
  const size_t SZ_WMT = (size_t)1024 * 1024 * 2;
  const size_t SZ_WFB = (size_t)128 * 1024 * 2;
  const size_t SZ_BSM = (size_t)4096 * 4;
  const size_t SZ_HB  = (size_t)BSZ * HDIM * 2;
  const size_t SZ_CF  = (size_t)BSZ * HDIM * 4;
  const size_t SZ_C2S = (size_t)TSTEPS * BSZ * HDIM * 2;

  char* base = (char*)d_ws;
  size_t off = 0;
  auto alloc = [&](size_t b) { char* p = base + off; off += (b + 255) & ~(size_t)255; return p; };

  u16*   Xbf    = (u16*)alloc(SZ_XBF);
  u16*   W1a    = (u16*)alloc(SZ_W1A);
  u16*   Whh1b  = (u16*)alloc(SZ_W1K);
  u16*   Wcombb = (u16*)alloc(SZ_W1K);
  u16*   Whh2b  = (u16*)alloc(SZ_W1K);
  u16*   Wih2b  = (u16*)alloc(SZ_W1K);
  u16*   WmidT  = (u16*)alloc(SZ_WMT);
  u16*   Wfinb  = (u16*)alloc(SZ_WFB);
  float* b1s    = (float*)alloc(SZ_BSM);
  float* b2s    = (float*)alloc(SZ_BSM);
  u16*   H1p[2]; H1p[0] = (u16*)alloc(SZ_HB); H1p[1] = (u16*)alloc(SZ_HB);
  u16*   H2p[2]; H2p[0] = (u16*)alloc(SZ_HB); H2p[1] = (u16*)alloc(SZ_HB);
  float* C1f    = (float*)alloc(SZ_CF);
  float* C2f    = (float*)alloc(SZ_CF);
  u16*   C1b    = (u16*)alloc(SZ_HB);
  u16*   C2b    = (u16*)alloc(SZ_HB);
  u16*   C2seq  = (u16*)(base + off);
  bool batched  = (off + SZ_C2S) <= ws_size;

  // zero states: H1p0,H1p1,H2p0,H2p1,C1f,C2f are contiguous (sizes 256-aligned)
  size_t zbytes = 4 * SZ_HB + 2 * SZ_CF;
  hipMemsetAsync((void*)H1p[0], 0, zbytes, stream);

  k_build_w1a<<<2048, 256, 0, stream>>>(Wih1, W1a);
  k_conv_perm1024<<<16384, 256, 0, stream>>>(Whh1, Whh1b);
  k_conv_perm1024<<<16384, 256, 0, stream>>>(Whh2, Whh2b);
  k_conv<<<16384, 256, 0, stream>>>(Wih2, Wih2b);
  k_transpose1024<<<4096, 256, 0, stream>>>(Wmid, WmidT);
  k_build_wfin<<<512, 256, 0, stream>>>(Wfin, Wfinb);
  k_build_xpad<<<46080, 256, 0, stream>>>(x, Xbf);
  k_b1sum<<<16, 256, 0, stream>>>(bih1, bhh1, b1s);
  k_b2sum<<<1024, 256, 0, stream>>>(Wih2, bmid, bih2, bhh2, b2s);
  wcomb_gemm<<<dim3(8, 64), 256, 0, stream>>>(Wih2b, WmidT, Wcombb);

  for (int t = 0; t < TSTEPS; ++t) {
    int p = t & 1;
    // cell 1: gates1 = Xpad[t]@W1a^T + h1@Whh1^T
    lstm_step<<<dim3(32, 8), 256, 0, stream>>>(
        Xbf + (size_t)t * BSZ * 128, W1a, 128,
        H1p[p], Whh1b, 1024, b1s, C1f, H1p[p ^ 1], C1b);
    // cell 2: gates2 = c1@Wcomb^T + h2@Whh2^T
    u16* c2dst = batched ? (C2seq + (size_t)t * BSZ * HDIM) : C2b;
    lstm_step<<<dim3(32, 8), 256, 0, stream>>>(
        C1b, Wcombb, 1024,
        H2p[p], Whh2b, 1024, b2s, C2f, H2p[p ^ 1], c2dst);
    if (!batched)
      final_logsoftmax<<<dim3(1, 8), 256, 0, stream>>>(
          C2b, Wfinb, bfin, (float*)d_out + (size_t)t * BSZ * VOUT);
  }
  if (batched)
    final_logsoftmax<<<dim3(1, (TSTEPS * BSZ) / 64), 256, 0, stream>>>(
        C2seq, Wfinb, bfin, (float*)d_out);
}

// Round 2
// 8827.507 us; speedup vs baseline: 1.2349x; 1.2349x over previous
//
#include <hip/hip_runtime.h>
#include <stdint.h>

// LSTM_34359738368754: 2-layer LSTM, T=180 B=512 H=1024 I=V=108.
// R2 strategy:
//  - W_comb = W_ih2 @ W_mid precomputed (mid-Linear folded).
//  - Gate-interleaved weight rows n' = 4*(n%1024)+gate -> cell update fuses
//    into GEMM epilogue via LDS round-trip.
//  - Per step 2 kernels:
//      K1 (256 blocks): [128 blk] gates1 = x_t@W1a^T + h1@Whh1^T -> cell1
//                       [128 blk] U2 = h2@Whh2^T + b2  (fp32, overlapped)
//      K2 (128 blocks): gates2 = c1@Wcomb^T + U2 -> cell2
//  - 128x128 tiles (m-blocks=4: halves weight re-read traffic vs 64-row),
//    BK=64, double-buffered LDS staging with raw s_barrier + vmcnt(8)
//    (m139-style pipeline; at 1 block/CU there is no cross-block overlap).
//  - c2 stored bf16 per step; one batched final GEMM + fused log_softmax.

typedef unsigned short u16;
typedef __attribute__((ext_vector_type(4))) float f32x4;
typedef __attribute__((ext_vector_type(8))) short bf16x8;

#define HDIM 1024
#define BSZ  512
#define TSTEPS 180
#define IIN  108
#define VOUT 108

__device__ __forceinline__ u16 f2bf(float x) {
  union { float f; unsigned u; } v; v.f = x;
  unsigned r = (v.u + 0x7fffu + ((v.u >> 16) & 1u)) >> 16;  // RNE
  return (u16)r;
}
__device__ __forceinline__ float sigm(float x) { return 1.f / (1.f + __expf(-x)); }
__device__ __forceinline__ float tanh_(float x) {
  float a = fabsf(x), t = __expf(-2.f * a);
  float r = (1.f - t) / (1.f + t);
  return x < 0.f ? -r : r;
}
__device__ __forceinline__ int permrow(int n) { return ((n & 1023) << 2) | (n >> 10); }

__device__ __forceinline__ void load16_lds(const void* g, void* l) {
  __builtin_amdgcn_global_load_lds(
      (const __attribute__((address_space(1))) unsigned int*)g,
      (__attribute__((address_space(3))) unsigned int*)l, 16, 0, 0);
}

// ================= 128x128 double-buffered GEMM =================
// smem: buf b at smem + b*32768; As 16KB then Bs 16KB. BK=64.
__device__ __forceinline__ void stage128(const u16* A, const u16* B, int K,
                                         int k0, int m0, int n0,
                                         char* smem, int buf, int wave, int lane) {
  u16* As = (u16*)(smem + buf * 32768);
  u16* Bs = (u16*)(smem + buf * 32768 + 16384);
#pragma unroll
  for (int i = 0; i < 4; ++i) {
    int c = (wave * 4 + i) * 64 + lane;
    const u16* g = A + (size_t)(m0 + (c >> 3)) * K + k0 + ((c & 7) << 3);
    load16_lds(g, As + c * 8);
  }
#pragma unroll
  for (int i = 0; i < 4; ++i) {
    int c = (wave * 4 + i) * 64 + lane;
    const u16* g = B + (size_t)(n0 + (c >> 3)) * K + k0 + ((c & 7) << 3);
    load16_lds(g, Bs + c * 8);
  }
}

__device__ __forceinline__ void compute128(f32x4 acc[4][4], char* smem, int buf,
                                           int wm, int wn, int l16, int quad) {
  const bf16x8* Av = (const bf16x8*)(smem + buf * 32768);
  const bf16x8* Bv = (const bf16x8*)(smem + buf * 32768 + 16384);
#pragma unroll
  for (int kk = 0; kk < 2; ++kk) {
    bf16x8 a[4], b[4];
#pragma unroll
    for (int mt = 0; mt < 4; ++mt)
      a[mt] = Av[(wm * 64 + mt * 16 + l16) * 8 + kk * 4 + quad];
#pragma unroll
    for (int nt = 0; nt < 4; ++nt)
      b[nt] = Bv[(wn * 64 + nt * 16 + l16) * 8 + kk * 4 + quad];
#pragma unroll
    for (int mt = 0; mt < 4; ++mt)
#pragma unroll
      for (int nt = 0; nt < 4; ++nt)
        acc[mt][nt] = __builtin_amdgcn_mfma_f32_16x16x32_bf16(
            a[mt], b[nt], acc[mt][nt], 0, 0, 0);
  }
}

// acc(128x128) at (m0,n0) = A0@B0^T (K0, optional) + A1@B1^T (K1).
template <bool HAS0>
__device__ __forceinline__ void gemm128(f32x4 acc[4][4],
    const u16* A0, const u16* B0, int K0,
    const u16* A1, const u16* B1, int K1,
    int m0, int n0, char* smem) {
  const int tid = threadIdx.x;
  const int lane = tid & 63, wave = tid >> 6;
  const int quad = lane >> 4, l16 = lane & 15;
  const int wm = wave >> 1, wn = wave & 1;

#pragma unroll
  for (int mt = 0; mt < 4; ++mt)
#pragma unroll
    for (int nt = 0; nt < 4; ++nt) {
      f32x4 z = {0.f, 0.f, 0.f, 0.f};
      acc[mt][nt] = z;
    }

  const int n0i = HAS0 ? (K0 >> 6) : 0;
  const int nIter = n0i + (K1 >> 6);

  // prologue: stage iter 0 into buf 0
  if (HAS0 && n0i > 0)
    stage128(A0, B0, K0, 0, m0, n0, smem, 0, wave, lane);
  else
    stage128(A1, B1, K1, 0, m0, n0, smem, 0, wave, lane);

  for (int it = 0; it < nIter; ++it) {
    if (it + 1 < nIter) {
      int nx = it + 1;
      if (HAS0 && nx < n0i)
        stage128(A0, B0, K0, nx * 64, m0, n0, smem, nx & 1, wave, lane);
      else
        stage128(A1, B1, K1, (nx - n0i) * 64, m0, n0, smem, nx & 1, wave, lane);
      __builtin_amdgcn_s_waitcnt(0xF78);  // vmcnt(8): prev stage landed
    } else {
      __builtin_amdgcn_s_waitcnt(0xF70);  // vmcnt(0)
    }
    __builtin_amdgcn_s_barrier();
    asm volatile("" ::: "memory");
    compute128(acc, smem, it & 1, wm, wn, l16, quad);
    asm volatile("" ::: "memory");
    __builtin_amdgcn_s_barrier();  // all waves done reading buf before overwrite
  }
}

// ============ K1: cell1 GEMM+update (blk<128)  ||  U2 GEMM (blk>=128) ============
__global__ __launch_bounds__(256, 1) void k1_fused(
    const u16* __restrict__ Xt, const u16* __restrict__ W1a,
    const u16* __restrict__ H1in, const u16* __restrict__ Whh1,
    const float* __restrict__ b1s, float* __restrict__ c1State,
    u16* __restrict__ H1out, u16* __restrict__ C1out,
    const u16* __restrict__ H2in, const u16* __restrict__ Whh2,
    const float* __restrict__ b2s, float* __restrict__ U2)
{
  __shared__ __align__(16) char smem[65536];
  const int tid = threadIdx.x;
  const int lane = tid & 63, wave = tid >> 6;
  const int quad = lane >> 4, l16 = lane & 15;
  const int wm = wave >> 1, wn = wave & 1;
  const int b = blockIdx.x;
  f32x4 acc[4][4];

  if (b < 128) {
    const int m0 = (b >> 5) * 128, n0 = (b & 31) * 128;
    gemm128<true>(acc, Xt, W1a, 128, H1in, Whh1, 1024, m0, n0, smem);

    float* gl = (float*)smem;  // [64][132]
    const int jbase = (b & 31) * 32;
#pragma unroll
    for (int h = 0; h < 2; ++h) {
      __syncthreads();
      if (wm == h) {
#pragma unroll
        for (int nt = 0; nt < 4; ++nt) {
          int col = wn * 64 + nt * 16 + l16;
#pragma unroll
          for (int mt = 0; mt < 4; ++mt) {
            int rowb = mt * 16 + quad * 4;
#pragma unroll
            for (int r = 0; r < 4; ++r)
              gl[(rowb + r) * 132 + col] = acc[mt][nt][r];
          }
        }
      }
      __syncthreads();
#pragma unroll
      for (int itr = 0; itr < 8; ++itr) {
        int idx = itr * 256 + tid;
        int mr = idx >> 5, jl = idx & 31;
        f32x4 g4 = *(const f32x4*)(gl + mr * 132 + jl * 4);
        f32x4 b4 = *(const f32x4*)(b1s + jbase * 4 + jl * 4);
        g4 += b4;
        float ii = sigm(g4[0]), ff = sigm(g4[1]);
        float gg = tanh_(g4[2]), oo = sigm(g4[3]);
        size_t off = (size_t)(m0 + h * 64 + mr) * HDIM + jbase + jl;
        float cp = c1State[off];
        float cn = ff * cp + ii * gg;
        float hh = oo * tanh_(cn);
        c1State[off] = cn;
        H1out[off] = f2bf(hh);
        C1out[off] = f2bf(cn);
      }
    }
  } else {
    const int bb = b - 128;
    const int m0 = (bb >> 5) * 128, n0 = (bb & 31) * 128;
    gemm128<false>(acc, nullptr, nullptr, 0, H2in, Whh2, 1024, m0, n0, smem);
#pragma unroll
    for (int nt = 0; nt < 4; ++nt) {
      int col = n0 + wn * 64 + nt * 16 + l16;
      float bias = b2s[col];
#pragma unroll
      for (int mt = 0; mt < 4; ++mt) {
        int row = m0 + wm * 64 + mt * 16 + quad * 4;
#pragma unroll
        for (int r = 0; r < 4; ++r)
          U2[(size_t)(row + r) * 4096 + col] = acc[mt][nt][r] + bias;
      }
    }
  }
}

// ============ K2: gates2 = c1@Wcomb^T + U2 -> cell2 update ============
__global__ __launch_bounds__(256, 1) void k2_cell2(
    const u16* __restrict__ C1b, const u16* __restrict__ Wcomb,
    const float* __restrict__ U2, float* __restrict__ c2State,
    u16* __restrict__ H2out, u16* __restrict__ C2out)
{
  __shared__ __align__(16) char smem[65536];
  const int tid = threadIdx.x;
  const int lane = tid & 63, wave = tid >> 6;
  const int quad = lane >> 4, l16 = lane & 15;
  const int wm = wave >> 1, wn = wave & 1;
  const int b = blockIdx.x;
  const int m0 = (b >> 5) * 128, n0 = (b & 31) * 128;
  f32x4 acc[4][4];
  gemm128<false>(acc, nullptr, nullptr, 0, C1b, Wcomb, 1024, m0, n0, smem);

  float* gl = (float*)smem;
  const int jbase = (b & 31) * 32;
#pragma unroll
  for (int h = 0; h < 2; ++h) {
    __syncthreads();
    if (wm == h) {
#pragma unroll
      for (int nt = 0; nt < 4; ++nt) {
        int col = wn * 64 + nt * 16 + l16;
#pragma unroll
        for (int mt = 0; mt < 4; ++mt) {
          int rowb = mt * 16 + quad * 4;
#pragma unroll
          for (int r = 0; r < 4; ++r)
            gl[(rowb + r) * 132 + col] = acc[mt][nt][r];
        }
      }
    }
    __syncthreads();
#pragma unroll
    for (int itr = 0; itr < 8; ++itr) {
      int idx = itr * 256 + tid;
      int mr = idx >> 5, jl = idx & 31;
      int grow = m0 + h * 64 + mr;
      f32x4 g4 = *(const f32x4*)(gl + mr * 132 + jl * 4);
      f32x4 u4 = *(const f32x4*)(U2 + (size_t)grow * 4096 + jbase * 4 + jl * 4);
      g4 += u4;
      float ii = sigm(g4[0]), ff = sigm(g4[1]);
      float gg = tanh_(g4[2]), oo = sigm(g4[3]);
      size_t off = (size_t)grow * HDIM + jbase + jl;
      float cp = c2State[off];
      float cn = ff * cp + ii * gg;
      float hh = oo * tanh_(cn);
      c2State[off] = cn;
      H2out[off] = f2bf(hh);
      C2out[off] = f2bf(cn);
    }
  }
}

// ================= 64x128 single-buffered GEMM (wcomb / final) =================
__device__ __forceinline__ void gemm_tile_64x128(
    f32x4 acc[2][4],
    const u16* A0, const u16* B0, int K0,
    const u16* A1, const u16* B1, int K1,
    int m0, int n0, u16* As, u16* Bs)
{
  const int tid  = threadIdx.x;
  const int lane = tid & 63;
  const int wave = tid >> 6;
  const int quad = lane >> 4;
  const int l16  = lane & 15;
  const int wm   = wave >> 1;
  const int wn   = wave & 1;

#pragma unroll
  for (int mt = 0; mt < 2; ++mt)
#pragma unroll
    for (int nt = 0; nt < 4; ++nt) {
      f32x4 z = {0.f, 0.f, 0.f, 0.f};
      acc[mt][nt] = z;
    }

  for (int s = 0; s < 2; ++s) {
    const u16* A = s ? A1 : A0;
    const u16* B = s ? B1 : B0;
    const int  K = s ? K1 : K0;
    for (int k0 = 0; k0 < K; k0 += 64) {
      __syncthreads();
#pragma unroll
      for (int i = 0; i < 2; ++i) {
        int chunk = (wave * 2 + i) * 64 + lane;
        const u16* g = A + (size_t)(m0 + (chunk >> 3)) * K + k0 + ((chunk & 7) << 3);
        load16_lds(g, As + (wave * 2 + i) * 512);
      }
#pragma unroll
      for (int i = 0; i < 4; ++i) {
        int chunk = (wave * 4 + i) * 64 + lane;
        const u16* g = B + (size_t)(n0 + (chunk >> 3)) * K + k0 + ((chunk & 7) << 3);
        load16_lds(g, Bs + (wave * 4 + i) * 512);
      }
      __syncthreads();
      const bf16x8* Av = (const bf16x8*)As;
      const bf16x8* Bv = (const bf16x8*)Bs;
#pragma unroll
      for (int kk = 0; kk < 2; ++kk) {
        bf16x8 a[2], b[4];
#pragma unroll
        for (int mt = 0; mt < 2; ++mt)
          a[mt] = Av[(wm * 32 + mt * 16 + l16) * 8 + kk * 4 + quad];
#pragma unroll
        for (int nt = 0; nt < 4; ++nt)
          b[nt] = Bv[(wn * 64 + nt * 16 + l16) * 8 + kk * 4 + quad];
#pragma unroll
        for (int mt = 0; mt < 2; ++mt)
#pragma unroll
          for (int nt = 0; nt < 4; ++nt)
            acc[mt][nt] = __builtin_amdgcn_mfma_f32_16x16x32_bf16(
                a[mt], b[nt], acc[mt][nt], 0, 0, 0);
      }
    }
  }
  __syncthreads();
}

__global__ __launch_bounds__(256, 2) void wcomb_gemm(
    const u16* __restrict__ A, const u16* __restrict__ Bt, u16* __restrict__ outp)
{
  __shared__ __align__(16) char smem[24576];
  u16* As = (u16*)smem;
  u16* Bs = (u16*)(smem + 8192);
  const int m0 = blockIdx.y * 64;
  const int n0 = blockIdx.x * 128;
  f32x4 acc[2][4];
  gemm_tile_64x128(acc, A, Bt, 1024, nullptr, nullptr, 0, m0, n0, As, Bs);
  const int lane = threadIdx.x & 63;
  const int wave = threadIdx.x >> 6;
  const int quad = lane >> 4, l16 = lane & 15;
  const int wm = wave >> 1, wn = wave & 1;
#pragma unroll
  for (int mt = 0; mt < 2; ++mt)
#pragma unroll
    for (int nt = 0; nt < 4; ++nt)
#pragma unroll
      for (int r = 0; r < 4; ++r) {
        int mr = m0 + wm * 32 + mt * 16 + quad * 4 + r;
        int c  = n0 + wn * 64 + nt * 16 + l16;
        outp[(size_t)permrow(mr) * 1024 + c] = f2bf(acc[mt][nt][r]);
      }
}

__global__ __launch_bounds__(256, 2) void final_logsoftmax(
    const u16* __restrict__ C2, const u16* __restrict__ Wf,
    const float* __restrict__ bfin, float* __restrict__ out)
{
  __shared__ __align__(16) char smem[64 * 132 * 4 + 256];
  u16* As = (u16*)smem;
  u16* Bs = (u16*)(smem + 8192);
  float* gl  = (float*)smem;
  float* lse = (float*)(smem + 64 * 132 * 4);

  const int m0 = blockIdx.y * 64;
  f32x4 acc[2][4];
  gemm_tile_64x128(acc, C2, Wf, 1024, nullptr, nullptr, 0, m0, 0, As, Bs);

  const int tid = threadIdx.x;
  const int lane = tid & 63;
  const int wave = tid >> 6;
  const int quad = lane >> 4, l16 = lane & 15;
  const int wm = wave >> 1, wn = wave & 1;
#pragma unroll
  for (int nt = 0; nt < 4; ++nt) {
    int coll = wn * 64 + nt * 16 + l16;
    float bias = (coll < VOUT) ? bfin[coll] : 0.f;
#pragma unroll
    for (int mt = 0; mt < 2; ++mt) {
      int rowb = wm * 32 + mt * 16 + quad * 4;
#pragma unroll
      for (int r = 0; r < 4; ++r)
        gl[(rowb + r) * 132 + coll] = acc[mt][nt][r] + bias;
    }
  }
  __syncthreads();
  if (tid < 64) {
    const float* row = gl + tid * 132;
    float mx = -1e30f;
    for (int c = 0; c < VOUT; ++c) mx = fmaxf(mx, row[c]);
    float s = 0.f;
    for (int c = 0; c < VOUT; ++c) s += __expf(row[c] - mx);
    lse[tid] = mx + __logf(s);
  }
  __syncthreads();
  for (int idx = tid; idx < 64 * VOUT; idx += 256) {
    int m = idx / VOUT, c = idx - m * VOUT;
    out[(size_t)(m0 + m) * VOUT + c] = gl[m * 132 + c] - lse[m];
  }
}

// ---------------- setup kernels ----------------
__global__ void k_build_w1a(const float* __restrict__ w, u16* __restrict__ d) {
  int idx = blockIdx.x * 256 + threadIdx.x;
  int n = idx >> 7, k = idx & 127;
  float v = (k < IIN) ? w[n * IIN + k] : 0.f;
  d[permrow(n) * 128 + k] = f2bf(v);
}
__global__ void k_conv_perm1024(const float* __restrict__ w, u16* __restrict__ d) {
  int idx = blockIdx.x * 256 + threadIdx.x;
  int n = idx >> 10, k = idx & 1023;
  d[(size_t)permrow(n) * 1024 + k] = f2bf(w[idx]);
}
__global__ void k_conv(const float* __restrict__ s, u16* __restrict__ d) {
  int idx = blockIdx.x * 256 + threadIdx.x;
  d[idx] = f2bf(s[idx]);
}
__global__ void k_transpose1024(const float* __restrict__ s, u16* __restrict__ d) {
  int idx = blockIdx.x * 256 + threadIdx.x;
  int r = idx >> 10, c = idx & 1023;
  d[c * 1024 + r] = f2bf(s[idx]);
}
__global__ void k_build_wfin(const float* __restrict__ w, u16* __restrict__ d) {
  int idx = blockIdx.x * 256 + threadIdx.x;
  int r = idx >> 10, c = idx & 1023;
  d[idx] = (r < VOUT) ? f2bf(w[r * 1024 + c]) : (u16)0;
}
__global__ void k_build_xpad(const float* __restrict__ x, u16* __restrict__ d) {
  int idx = blockIdx.x * 256 + threadIdx.x;
  int row = idx >> 7, k = idx & 127;
  d[idx] = (k < IIN) ? f2bf(x[row * IIN + k]) : (u16)0;
}
__global__ void k_b1sum(const float* __restrict__ a, const float* __restrict__ b,
                        float* __restrict__ d) {
  int n = blockIdx.x * 256 + threadIdx.x;
  d[permrow(n)] = a[n] + b[n];
}
__global__ void k_b2sum(const float* __restrict__ Wih2, const float* __restrict__ bmid,
                        const float* __restrict__ bih2, const float* __restrict__ bhh2,
                        float* __restrict__ d) {
  int row = blockIdx.x * 4 + (threadIdx.x >> 6);
  int lane = threadIdx.x & 63;
  const float* wr = Wih2 + (size_t)row * 1024;
  float s = 0.f;
  for (int k = lane; k < 1024; k += 64) s += wr[k] * bmid[k];
#pragma unroll
  for (int o = 32; o > 0; o >>= 1) s += __shfl_down(s, o);
  if (lane == 0) d[permrow(row)] = s + bih2[row] + bhh2[row];
}

extern "C" void kernel_launch(void* const* d_in, const int* in_sizes, int n_in,
                              void* d_out, int out_size, void* d_ws, size_t ws_size,
                              hipStream_t stream) {
  const float* x    = (const float*)d_in[0];
  const float* Wih1 = (const float*)d_in[1];
  const float* Whh1 = (const float*)d_in[2];
  const float* bih1 = (const float*)d_in[3];
  const float* bhh1 = (const float*)d_in[4];
  const float* Wmid = (const float*)d_in[5];
  const float* bmid = (const float*)d_in[6];
  const float* Wih2 = (const float*)d_in[7];
  const float* Whh2 = (const float*)d_in[8];
  const float* bih2 = (const float*)d_in[9];
  const float* bhh2 = (const float*)d_in[10];
  const float* Wfin = (const float*)d_in[11];
  const float* bfin = (const float*)d_in[12];

  const size_t SZ_XBF = (size_t)TSTEPS * BSZ * 128 * 2;
  const size_t SZ_W1A = (size_t)4096 * 128 * 2;
  const size_t SZ_W1K = (size_t)4096 * 1024 * 2;
  const size_t SZ_WMT = (size_t)1024 * 1024 * 2;
  const size_t SZ_WFB = (size_t)128 * 1024 * 2;
  const size_t SZ_BSM = (size_t)4096 * 4;
  const size_t SZ_HB  = (size_t)BSZ * HDIM * 2;
  const size_t SZ_CF  = (size_t)BSZ * HDIM * 4;
  const size_t SZ_U2  = (size_t)BSZ * 4096 * 4;
  const size_t SZ_C2S = (size_t)TSTEPS * BSZ * HDIM * 2;

  char* base = (char*)d_ws;
  size_t off = 0;
  auto alloc = [&](size_t b) { char* p = base + off; off += (b + 255) & ~(size_t)255; return p; };

  u16*   Xbf    = (u16*)alloc(SZ_XBF);
  u16*   W1a    = (u16*)alloc(SZ_W1A);
  u16*   Whh1b  = (u16*)alloc(SZ_W1K);
  u16*   Wcombb = (u16*)alloc(SZ_W1K);
  u16*   Whh2b  = (u16*)alloc(SZ_W1K);
  u16*   Wih2b  = (u16*)alloc(SZ_W1K);
  u16*   WmidT  = (u16*)alloc(SZ_WMT);
  u16*   Wfinb  = (u16*)alloc(SZ_WFB);
  float* b1s    = (float*)alloc(SZ_BSM);
  float* b2s    = (float*)alloc(SZ_BSM);
  u16*   H1p[2]; H1p[0] = (u16*)alloc(SZ_HB); H1p[1] = (u16*)alloc(SZ_HB);
  u16*   H2p[2]; H2p[0] = (u16*)alloc(SZ_HB); H2p[1] = (u16*)alloc(SZ_HB);
  float* C1f    = (float*)alloc(SZ_CF);
  float* C2f    = (float*)alloc(SZ_CF);
  u16*   C1b    = (u16*)alloc(SZ_HB);
  u16*   C2b    = (u16*)alloc(SZ_HB);
  float* U2     = (float*)alloc(SZ_U2);
  u16*   C2seq  = (u16*)(base + off);
  bool batched  = (off + SZ_C2S) <= ws_size;

  // zero states: H1p0,H1p1,H2p0,H2p1,C1f,C2f contiguous (256-aligned sizes)
  size_t zbytes = 4 * SZ_HB + 2 * SZ_CF;
  hipMemsetAsync((void*)H1p[0], 0, zbytes, stream);

  k_build_w1a<<<2048, 256, 0, stream>>>(Wih1, W1a);
  k_conv_perm1024<<<16384, 256, 0, stream>>>(Whh1, Whh1b);
  k_conv_perm1024<<<16384, 256, 0, stream>>>(Whh2, Whh2b);
  k_conv<<<16384, 256, 0, stream>>>(Wih2, Wih2b);
  k_transpose1024<<<4096, 256, 0, stream>>>(Wmid, WmidT);
  k_build_wfin<<<512, 256, 0, stream>>>(Wfin, Wfinb);
  k_build_xpad<<<46080, 256, 0, stream>>>(x, Xbf);
  k_b1sum<<<16, 256, 0, stream>>>(bih1, bhh1, b1s);
  k_b2sum<<<1024, 256, 0, stream>>>(Wih2, bmid, bih2, bhh2, b2s);
  wcomb_gemm<<<dim3(8, 64), 256, 0, stream>>>(Wih2b, WmidT, Wcombb);

  for (int t = 0; t < TSTEPS; ++t) {
    int p = t & 1;
    k1_fused<<<256, 256, 0, stream>>>(
        Xbf + (size_t)t * BSZ * 128, W1a, H1p[p], Whh1b, b1s, C1f,
        H1p[p ^ 1], C1b, H2p[p], Whh2b, b2s, U2);
    u16* c2dst = batched ? (C2seq + (size_t)t * BSZ * HDIM) : C2b;
    k2_cell2<<<128, 256, 0, stream>>>(C1b, Wcombb, U2, C2f, H2p[p ^ 1], c2dst);
    if (!batched)
      final_logsoftmax<<<dim3(1, 8), 256, 0, stream>>>(
          C2b, Wfinb, bfin, (float*)d_out + (size_t)t * BSZ * VOUT);
  }
  if (batched)
    final_logsoftmax<<<dim3(1, (TSTEPS * BSZ) / 64), 256, 0, stream>>>(
        C2seq, Wfinb, bfin, (float*)d_out);
}

// Round 3
// 7606.374 us; speedup vs baseline: 1.4331x; 1.1605x over previous
//
#include <hip/hip_runtime.h>
#include <stdint.h>

// LSTM_34359738368754: 2-layer LSTM, T=180 B=512 H=1024 I=V=108.
// R3: R2 structure + XOR-swizzled LDS layout (kills 16-way bank conflicts
//     in fragment ds_read_b128s -> 2-way ~free) + U2 stored bf16.
//  - W_comb = W_ih2 @ W_mid precomputed (mid-Linear folded).
//  - Gate-interleaved weight rows n' = 4*(n%1024)+gate -> cell update fuses
//    into GEMM epilogue via LDS round-trip.
//  - Per step 2 kernels:
//      K1 (256 blocks): [128 blk] gates1 = x_t@W1a^T + h1@Whh1^T -> cell1
//                       [128 blk] U2 = h2@Whh2^T + b2  (bf16, overlapped)
//      K2 (128 blocks): gates2 = c1@Wcomb^T + U2 -> cell2
//  - 128x128 tiles, BK=64, double-buffered LDS, raw s_barrier + vmcnt(8).
//  - c2 stored bf16 per step; one batched final GEMM + fused log_softmax.

typedef unsigned short u16;
typedef __attribute__((ext_vector_type(4))) float f32x4;
typedef __attribute__((ext_vector_type(8))) short bf16x8;

#define HDIM 1024
#define BSZ  512
#define TSTEPS 180
#define IIN  108
#define VOUT 108

__device__ __forceinline__ u16 f2bf(float x) {
  union { float f; unsigned u; } v; v.f = x;
  unsigned r = (v.u + 0x7fffu + ((v.u >> 16) & 1u)) >> 16;  // RNE
  return (u16)r;
}
__device__ __forceinline__ float bf2f(u16 b) {
  union { unsigned u; float f; } v; v.u = ((unsigned)b) << 16; return v.f;
}
__device__ __forceinline__ float sigm(float x) { return 1.f / (1.f + __expf(-x)); }
__device__ __forceinline__ float tanh_(float x) {
  float a = fabsf(x), t = __expf(-2.f * a);
  float r = (1.f - t) / (1.f + t);
  return x < 0.f ? -r : r;
}
__device__ __forceinline__ int permrow(int n) { return ((n & 1023) << 2) | (n >> 10); }

__device__ __forceinline__ void load16_lds(const void* g, void* l) {
  __builtin_amdgcn_global_load_lds(
      (const __attribute__((address_space(1))) unsigned int*)g,
      (__attribute__((address_space(3))) unsigned int*)l, 16, 0, 0);
}

// ================= 128x128 double-buffered GEMM =================
// smem: buf b at smem + b*32768; As 16KB then Bs 16KB. BK=64.
// LDS chunk swizzle: physical chunk pc holds logical chunk pc^(row&7).
__device__ __forceinline__ void stage128(const u16* A, const u16* B, int K,
                                         int k0, int m0, int n0,
                                         char* smem, int buf, int wave, int lane) {
  u16* As = (u16*)(smem + buf * 32768);
  u16* Bs = (u16*)(smem + buf * 32768 + 16384);
#pragma unroll
  for (int i = 0; i < 4; ++i) {
    int c = (wave * 4 + i) * 64 + lane;
    int row = c >> 3, lc = (c & 7) ^ (row & 7);     // swizzled source chunk
    const u16* g = A + (size_t)(m0 + row) * K + k0 + (lc << 3);
    load16_lds(g, As + c * 8);
  }
#pragma unroll
  for (int i = 0; i < 4; ++i) {
    int c = (wave * 4 + i) * 64 + lane;
    int row = c >> 3, lc = (c & 7) ^ (row & 7);
    const u16* g = B + (size_t)(n0 + row) * K + k0 + (lc << 3);
    load16_lds(g, Bs + c * 8);
  }
}

__device__ __forceinline__ void compute128(f32x4 acc[4][4], char* smem, int buf,
                                           int wm, int wn, int l16, int quad) {
  const bf16x8* Av = (const bf16x8*)(smem + buf * 32768);
  const bf16x8* Bv = (const bf16x8*)(smem + buf * 32768 + 16384);
  const int sw = l16 & 7;
#pragma unroll
  for (int kk = 0; kk < 2; ++kk) {
    const int pc = (kk * 4 + quad) ^ sw;            // swizzled chunk
    bf16x8 a[4], b[4];
#pragma unroll
    for (int mt = 0; mt < 4; ++mt)
      a[mt] = Av[(wm * 64 + mt * 16 + l16) * 8 + pc];
#pragma unroll
    for (int nt = 0; nt < 4; ++nt)
      b[nt] = Bv[(wn * 64 + nt * 16 + l16) * 8 + pc];
#pragma unroll
    for (int mt = 0; mt < 4; ++mt)
#pragma unroll
      for (int nt = 0; nt < 4; ++nt)
        acc[mt][nt] = __builtin_amdgcn_mfma_f32_16x16x32_bf16(
            a[mt], b[nt], acc[mt][nt], 0, 0, 0);
  }
}

// acc(128x128) at (m0,n0) = A0@B0^T (K0, optional) + A1@B1^T (K1).
template <bool HAS0>
__device__ __forceinline__ void gemm128(f32x4 acc[4][4],
    const u16* A0, const u16* B0, int K0,
    const u16* A1, const u16* B1, int K1,
    int m0, int n0, char* smem) {
  const int tid = threadIdx.x;
  const int lane = tid & 63, wave = tid >> 6;
  const int quad = lane >> 4, l16 = lane & 15;
  const int wm = wave >> 1, wn = wave & 1;

#pragma unroll
  for (int mt = 0; mt < 4; ++mt)
#pragma unroll
    for (int nt = 0; nt < 4; ++nt) {
      f32x4 z = {0.f, 0.f, 0.f, 0.f};
      acc[mt][nt] = z;
    }

  const int n0i = HAS0 ? (K0 >> 6) : 0;
  const int nIter = n0i + (K1 >> 6);

  // prologue: stage iter 0 into buf 0
  if (HAS0 && n0i > 0)
    stage128(A0, B0, K0, 0, m0, n0, smem, 0, wave, lane);
  else
    stage128(A1, B1, K1, 0, m0, n0, smem, 0, wave, lane);

  for (int it = 0; it < nIter; ++it) {
    if (it + 1 < nIter) {
      int nx = it + 1;
      if (HAS0 && nx < n0i)
        stage128(A0, B0, K0, nx * 64, m0, n0, smem, nx & 1, wave, lane);
      else
        stage128(A1, B1, K1, (nx - n0i) * 64, m0, n0, smem, nx & 1, wave, lane);
      __builtin_amdgcn_s_waitcnt(0xF78);  // vmcnt(8): prev stage landed
    } else {
      __builtin_amdgcn_s_waitcnt(0xF70);  // vmcnt(0)
    }
    __builtin_amdgcn_s_barrier();
    asm volatile("" ::: "memory");
    compute128(acc, smem, it & 1, wm, wn, l16, quad);
    asm volatile("" ::: "memory");
    __builtin_amdgcn_s_barrier();  // all waves done reading buf before overwrite
  }
}

// ============ K1: cell1 GEMM+update (blk<128)  ||  U2 GEMM (blk>=128) ============
__global__ __launch_bounds__(256, 1) void k1_fused(
    const u16* __restrict__ Xt, const u16* __restrict__ W1a,
    const u16* __restrict__ H1in, const u16* __restrict__ Whh1,
    const float* __restrict__ b1s, float* __restrict__ c1State,
    u16* __restrict__ H1out, u16* __restrict__ C1out,
    const u16* __restrict__ H2in, const u16* __restrict__ Whh2,
    const float* __restrict__ b2s, u16* __restrict__ U2)
{
  __shared__ __align__(16) char smem[65536];
  const int tid = threadIdx.x;
  const int lane = tid & 63, wave = tid >> 6;
  const int quad = lane >> 4, l16 = lane & 15;
  const int wm = wave >> 1, wn = wave & 1;
  const int b = blockIdx.x;
  f32x4 acc[4][4];

  if (b < 128) {
    const int m0 = (b >> 5) * 128, n0 = (b & 31) * 128;
    gemm128<true>(acc, Xt, W1a, 128, H1in, Whh1, 1024, m0, n0, smem);

    float* gl = (float*)smem;  // [64][132]
    const int jbase = (b & 31) * 32;
#pragma unroll
    for (int h = 0; h < 2; ++h) {
      __syncthreads();
      if (wm == h) {
#pragma unroll
        for (int nt = 0; nt < 4; ++nt) {
          int col = wn * 64 + nt * 16 + l16;
#pragma unroll
          for (int mt = 0; mt < 4; ++mt) {
            int rowb = mt * 16 + quad * 4;
#pragma unroll
            for (int r = 0; r < 4; ++r)
              gl[(rowb + r) * 132 + col] = acc[mt][nt][r];
          }
        }
      }
      __syncthreads();
#pragma unroll
      for (int itr = 0; itr < 8; ++itr) {
        int idx = itr * 256 + tid;
        int mr = idx >> 5, jl = idx & 31;
        f32x4 g4 = *(const f32x4*)(gl + mr * 132 + jl * 4);
        f32x4 b4 = *(const f32x4*)(b1s + jbase * 4 + jl * 4);
        g4 += b4;
        float ii = sigm(g4[0]), ff = sigm(g4[1]);
        float gg = tanh_(g4[2]), oo = sigm(g4[3]);
        size_t off = (size_t)(m0 + h * 64 + mr) * HDIM + jbase + jl;
        float cp = c1State[off];
        float cn = ff * cp + ii * gg;
        float hh = oo * tanh_(cn);
        c1State[off] = cn;
        H1out[off] = f2bf(hh);
        C1out[off] = f2bf(cn);
      }
    }
  } else {
    const int bb = b - 128;
    const int m0 = (bb >> 5) * 128, n0 = (bb & 31) * 128;
    gemm128<false>(acc, nullptr, nullptr, 0, H2in, Whh2, 1024, m0, n0, smem);
#pragma unroll
    for (int nt = 0; nt < 4; ++nt) {
      int col = n0 + wn * 64 + nt * 16 + l16;
      float bias = b2s[col];
#pragma unroll
      for (int mt = 0; mt < 4; ++mt) {
        int row = m0 + wm * 64 + mt * 16 + quad * 4;
#pragma unroll
        for (int r = 0; r < 4; ++r)
          U2[(size_t)(row + r) * 4096 + col] = f2bf(acc[mt][nt][r] + bias);
      }
    }
  }
}

// ============ K2: gates2 = c1@Wcomb^T + U2 -> cell2 update ============
__global__ __launch_bounds__(256, 1) void k2_cell2(
    const u16* __restrict__ C1b, const u16* __restrict__ Wcomb,
    const u16* __restrict__ U2, float* __restrict__ c2State,
    u16* __restrict__ H2out, u16* __restrict__ C2out)
{
  __shared__ __align__(16) char smem[65536];
  const int tid = threadIdx.x;
  const int lane = tid & 63, wave = tid >> 6;
  const int quad = lane >> 4, l16 = lane & 15;
  const int wm = wave >> 1, wn = wave & 1;
  const int b = blockIdx.x;
  const int m0 = (b >> 5) * 128, n0 = (b & 31) * 128;
  f32x4 acc[4][4];
  gemm128<false>(acc, nullptr, nullptr, 0, C1b, Wcomb, 1024, m0, n0, smem);

  float* gl = (float*)smem;
  const int jbase = (b & 31) * 32;
#pragma unroll
  for (int h = 0; h < 2; ++h) {
    __syncthreads();
    if (wm == h) {
#pragma unroll
      for (int nt = 0; nt < 4; ++nt) {
        int col = wn * 64 + nt * 16 + l16;
#pragma unroll
        for (int mt = 0; mt < 4; ++mt) {
          int rowb = mt * 16 + quad * 4;
#pragma unroll
          for (int r = 0; r < 4; ++r)
            gl[(rowb + r) * 132 + col] = acc[mt][nt][r];
        }
      }
    }
    __syncthreads();
#pragma unroll
    for (int itr = 0; itr < 8; ++itr) {
      int idx = itr * 256 + tid;
      int mr = idx >> 5, jl = idx & 31;
      int grow = m0 + h * 64 + mr;
      f32x4 g4 = *(const f32x4*)(gl + mr * 132 + jl * 4);
      const u16* u2p = U2 + (size_t)grow * 4096 + jbase * 4 + jl * 4;
      g4[0] += bf2f(u2p[0]); g4[1] += bf2f(u2p[1]);
      g4[2] += bf2f(u2p[2]); g4[3] += bf2f(u2p[3]);
      float ii = sigm(g4[0]), ff = sigm(g4[1]);
      float gg = tanh_(g4[2]), oo = sigm(g4[3]);
      size_t off = (size_t)grow * HDIM + jbase + jl;
      float cp = c2State[off];
      float cn = ff * cp + ii * gg;
      float hh = oo * tanh_(cn);
      c2State[off] = cn;
      H2out[off] = f2bf(hh);
      C2out[off] = f2bf(cn);
    }
  }
}

// ================= 64x128 single-buffered GEMM (wcomb / final) =================
__device__ __forceinline__ void gemm_tile_64x128(
    f32x4 acc[2][4],
    const u16* A0, const u16* B0, int K0,
    const u16* A1, const u16* B1, int K1,
    int m0, int n0, u16* As, u16* Bs)
{
  const int tid  = threadIdx.x;
  const int lane = tid & 63;
  const int wave = tid >> 6;
  const int quad = lane >> 4;
  const int l16  = lane & 15;
  const int wm   = wave >> 1;
  const int wn   = wave & 1;
  const int sw   = l16 & 7;

#pragma unroll
  for (int mt = 0; mt < 2; ++mt)
#pragma unroll
    for (int nt = 0; nt < 4; ++nt) {
      f32x4 z = {0.f, 0.f, 0.f, 0.f};
      acc[mt][nt] = z;
    }

  for (int s = 0; s < 2; ++s) {
    const u16* A = s ? A1 : A0;
    const u16* B = s ? B1 : B0;
    const int  K = s ? K1 : K0;
    for (int k0 = 0; k0 < K; k0 += 64) {
      __syncthreads();
#pragma unroll
      for (int i = 0; i < 2; ++i) {
        int c = (wave * 2 + i) * 64 + lane;
        int row = c >> 3, lc = (c & 7) ^ (row & 7);
        const u16* g = A + (size_t)(m0 + row) * K + k0 + (lc << 3);
        load16_lds(g, As + c * 8);
      }
#pragma unroll
      for (int i = 0; i < 4; ++i) {
        int c = (wave * 4 + i) * 64 + lane;
        int row = c >> 3, lc = (c & 7) ^ (row & 7);
        const u16* g = B + (size_t)(n0 + row) * K + k0 + (lc << 3);
        load16_lds(g, Bs + c * 8);
      }
      __syncthreads();
      const bf16x8* Av = (const bf16x8*)As;
      const bf16x8* Bv = (const bf16x8*)Bs;
#pragma unroll
      for (int kk = 0; kk < 2; ++kk) {
        const int pc = (kk * 4 + quad) ^ sw;
        bf16x8 a[2], b[4];
#pragma unroll
        for (int mt = 0; mt < 2; ++mt)
          a[mt] = Av[(wm * 32 + mt * 16 + l16) * 8 + pc];
#pragma unroll
        for (int nt = 0; nt < 4; ++nt)
          b[nt] = Bv[(wn * 64 + nt * 16 + l16) * 8 + pc];
#pragma unroll
        for (int mt = 0; mt < 2; ++mt)
#pragma unroll
          for (int nt = 0; nt < 4; ++nt)
            acc[mt][nt] = __builtin_amdgcn_mfma_f32_16x16x32_bf16(
                a[mt], b[nt], acc[mt][nt], 0, 0, 0);
      }
    }
  }
  __syncthreads();
}

__global__ __launch_bounds__(256, 2) void wcomb_gemm(
    const u16* __restrict__ A, const u16* __restrict__ Bt, u16* __restrict__ outp)
{
  __shared__ __align__(16) char smem[24576];
  u16* As = (u16*)smem;
  u16* Bs = (u16*)(smem + 8192);
  const int m0 = blockIdx.y * 64;
  const int n0 = blockIdx.x * 128;
  f32x4 acc[2][4];
  gemm_tile_64x128(acc, A, Bt, 1024, nullptr, nullptr, 0, m0, n0, As, Bs);
  const int lane = threadIdx.x & 63;
  const int wave = threadIdx.x >> 6;
  const int quad = lane >> 4, l16 = lane & 15;
  const int wm = wave >> 1, wn = wave & 1;
#pragma unroll
  for (int mt = 0; mt < 2; ++mt)
#pragma unroll
    for (int nt = 0; nt < 4; ++nt)
#pragma unroll
      for (int r = 0; r < 4; ++r) {
        int mr = m0 + wm * 32 + mt * 16 + quad * 4 + r;
        int c  = n0 + wn * 64 + nt * 16 + l16;
        outp[(size_t)permrow(mr) * 1024 + c] = f2bf(acc[mt][nt][r]);
      }
}

__global__ __launch_bounds__(256, 2) void final_logsoftmax(
    const u16* __restrict__ C2, const u16* __restrict__ Wf,
    const float* __restrict__ bfin, float* __restrict__ out)
{
  __shared__ __align__(16) char smem[64 * 132 * 4 + 256];
  u16* As = (u16*)smem;
  u16* Bs = (u16*)(smem + 8192);
  float* gl  = (float*)smem;
  float* lse = (float*)(smem + 64 * 132 * 4);

  const int m0 = blockIdx.y * 64;
  f32x4 acc[2][4];
  gemm_tile_64x128(acc, C2, Wf, 1024, nullptr, nullptr, 0, m0, 0, As, Bs);

  const int tid = threadIdx.x;
  const int lane = tid & 63;
  const int wave = tid >> 6;
  const int quad = lane >> 4, l16 = lane & 15;
  const int wm = wave >> 1, wn = wave & 1;
#pragma unroll
  for (int nt = 0; nt < 4; ++nt) {
    int coll = wn * 64 + nt * 16 + l16;
    float bias = (coll < VOUT) ? bfin[coll] : 0.f;
#pragma unroll
    for (int mt = 0; mt < 2; ++mt) {
      int rowb = wm * 32 + mt * 16 + quad * 4;
#pragma unroll
      for (int r = 0; r < 4; ++r)
        gl[(rowb + r) * 132 + coll] = acc[mt][nt][r] + bias;
    }
  }
  __syncthreads();
  if (tid < 64) {
    const float* row = gl + tid * 132;
    float mx = -1e30f;
    for (int c = 0; c < VOUT; ++c) mx = fmaxf(mx, row[c]);
    float s = 0.f;
    for (int c = 0; c < VOUT; ++c) s += __expf(row[c] - mx);
    lse[tid] = mx + __logf(s);
  }
  __syncthreads();
  for (int idx = tid; idx < 64 * VOUT; idx += 256) {
    int m = idx / VOUT, c = idx - m * VOUT;
    out[(size_t)(m0 + m) * VOUT + c] = gl[m * 132 + c] - lse[m];
  }
}

// ---------------- setup kernels ----------------
__global__ void k_build_w1a(const float* __restrict__ w, u16* __restrict__ d) {
  int idx = blockIdx.x * 256 + threadIdx.x;
  int n = idx >> 7, k = idx & 127;
  float v = (k < IIN) ? w[n * IIN + k] : 0.f;
  d[permrow(n) * 128 + k] = f2bf(v);
}
__global__ void k_conv_perm1024(const float* __restrict__ w, u16* __restrict__ d) {
  int idx = blockIdx.x * 256 + threadIdx.x;
  int n = idx >> 10, k = idx & 1023;
  d[(size_t)permrow(n) * 1024 + k] = f2bf(w[idx]);
}
__global__ void k_conv(const float* __restrict__ s, u16* __restrict__ d) {
  int idx = blockIdx.x * 256 + threadIdx.x;
  d[idx] = f2bf(s[idx]);
}
__global__ void k_transpose1024(const float* __restrict__ s, u16* __restrict__ d) {
  int idx = blockIdx.x * 256 + threadIdx.x;
  int r = idx >> 10, c = idx & 1023;
  d[c * 1024 + r] = f2bf(s[idx]);
}
__global__ void k_build_wfin(const float* __restrict__ w, u16* __restrict__ d) {
  int idx = blockIdx.x * 256 + threadIdx.x;
  int r = idx >> 10, c = idx & 1023;
  d[idx] = (r < VOUT) ? f2bf(w[r * 1024 + c]) : (u16)0;
}
__global__ void k_build_xpad(const float* __restrict__ x, u16* __restrict__ d) {
  int idx = blockIdx.x * 256 + threadIdx.x;
  int row = idx >> 7, k = idx & 127;
  d[idx] = (k < IIN) ? f2bf(x[row * IIN + k]) : (u16)0;
}
__global__ void k_b1sum(const float* __restrict__ a, const float* __restrict__ b,
                        float* __restrict__ d) {
  int n = blockIdx.x * 256 + threadIdx.x;
  d[permrow(n)] = a[n] + b[n];
}
__global__ void k_b2sum(const float* __restrict__ Wih2, const float* __restrict__ bmid,
                        const float* __restrict__ bih2, const float* __restrict__ bhh2,
                        float* __restrict__ d) {
  int row = blockIdx.x * 4 + (threadIdx.x >> 6);
  int lane = threadIdx.x & 63;
  const float* wr = Wih2 + (size_t)row * 1024;
  float s = 0.f;
  for (int k = lane; k < 1024; k += 64) s += wr[k] * bmid[k];
#pragma unroll
  for (int o = 32; o > 0; o >>= 1) s += __shfl_down(s, o);
  if (lane == 0) d[permrow(row)] = s + bih2[row] + bhh2[row];
}

extern "C" void kernel_launch(void* const* d_in, const int* in_sizes, int n_in,
                              void* d_out, int out_size, void* d_ws, size_t ws_size,
                              hipStream_t stream) {
  const float* x    = (const float*)d_in[0];
  const float* Wih1 = (const float*)d_in[1];
  const float* Whh1 = (const float*)d_in[2];
  const float* bih1 = (const float*)d_in[3];
  const float* bhh1 = (const float*)d_in[4];
  const float* Wmid = (const float*)d_in[5];
  const float* bmid = (const float*)d_in[6];
  const float* Wih2 = (const float*)d_in[7];
  const float* Whh2 = (const float*)d_in[8];
  const float* bih2 = (const float*)d_in[9];
  const float* bhh2 = (const float*)d_in[10];
  const float* Wfin = (const float*)d_in[11];
  const float* bfin = (const float*)d_in[12];

  const size_t SZ_XBF = (size_t)TSTEPS * BSZ * 128 * 2;
  const size_t SZ_W1A = (size_t)4096 * 128 * 2;
  const size_t SZ_W1K = (size_t)4096 * 1024 * 2;
  const size_t SZ_WMT = (size_t)1024 * 1024 * 2;
  const size_t SZ_WFB = (size_t)128 * 1024 * 2;
  const size_t SZ_BSM = (size_t)4096 * 4;
  const size_t SZ_HB  = (size_t)BSZ * HDIM * 2;
  const size_t SZ_CF  = (size_t)BSZ * HDIM * 4;
  const size_t SZ_U2  = (size_t)BSZ * 4096 * 2;
  const size_t SZ_C2S = (size_t)TSTEPS * BSZ * HDIM * 2;

  char* base = (char*)d_ws;
  size_t off = 0;
  auto alloc = [&](size_t b) { char* p = base + off; off += (b + 255) & ~(size_t)255; return p; };

  u16*   Xbf    = (u16*)alloc(SZ_XBF);
  u16*   W1a    = (u16*)alloc(SZ_W1A);
  u16*   Whh1b  = (u16*)alloc(SZ_W1K);
  u16*   Wcombb = (u16*)alloc(SZ_W1K);
  u16*   Whh2b  = (u16*)alloc(SZ_W1K);
  u16*   Wih2b  = (u16*)alloc(SZ_W1K);
  u16*   WmidT  = (u16*)alloc(SZ_WMT);
  u16*   Wfinb  = (u16*)alloc(SZ_WFB);
  float* b1s    = (float*)alloc(SZ_BSM);
  float* b2s    = (float*)alloc(SZ_BSM);
  u16*   H1p[2]; H1p[0] = (u16*)alloc(SZ_HB); H1p[1] = (u16*)alloc(SZ_HB);
  u16*   H2p[2]; H2p[0] = (u16*)alloc(SZ_HB); H2p[1] = (u16*)alloc(SZ_HB);
  float* C1f    = (float*)alloc(SZ_CF);
  float* C2f    = (float*)alloc(SZ_CF);
  u16*   C1b    = (u16*)alloc(SZ_HB);
  u16*   C2b    = (u16*)alloc(SZ_HB);
  u16*   U2     = (u16*)alloc(SZ_U2);
  u16*   C2seq  = (u16*)(base + off);
  bool batched  = (off + SZ_C2S) <= ws_size;

  // zero states: H1p0,H1p1,H2p0,H2p1,C1f,C2f contiguous (256-aligned sizes)
  size_t zbytes = 4 * SZ_HB + 2 * SZ_CF;
  hipMemsetAsync((void*)H1p[0], 0, zbytes, stream);

  k_build_w1a<<<2048, 256, 0, stream>>>(Wih1, W1a);
  k_conv_perm1024<<<16384, 256, 0, stream>>>(Whh1, Whh1b);
  k_conv_perm1024<<<16384, 256, 0, stream>>>(Whh2, Whh2b);
  k_conv<<<16384, 256, 0, stream>>>(Wih2, Wih2b);
  k_transpose1024<<<4096, 256, 0, stream>>>(Wmid, WmidT);
  k_build_wfin<<<512, 256, 0, stream>>>(Wfin, Wfinb);
  k_build_xpad<<<46080, 256, 0, stream>>>(x, Xbf);
  k_b1sum<<<16, 256, 0, stream>>>(bih1, bhh1, b1s);
  k_b2sum<<<1024, 256, 0, stream>>>(Wih2, bmid, bih2, bhh2, b2s);
  wcomb_gemm<<<dim3(8, 64), 256, 0, stream>>>(Wih2b, WmidT, Wcombb);

  for (int t = 0; t < TSTEPS; ++t) {
    int p = t & 1;
    k1_fused<<<256, 256, 0, stream>>>(
        Xbf + (size_t)t * BSZ * 128, W1a, H1p[p], Whh1b, b1s, C1f,
        H1p[p ^ 1], C1b, H2p[p], Whh2b, b2s, U2);
    u16* c2dst = batched ? (C2seq + (size_t)t * BSZ * HDIM) : C2b;
    k2_cell2<<<128, 256, 0, stream>>>(C1b, Wcombb, U2, C2f, H2p[p ^ 1], c2dst);
    if (!batched)
      final_logsoftmax<<<dim3(1, 8), 256, 0, stream>>>(
          C2b, Wfinb, bfin, (float*)d_out + (size_t)t * BSZ * VOUT);
  }
  if (batched)
    final_logsoftmax<<<dim3(1, (TSTEPS * BSZ) / 64), 256, 0, stream>>>(
        C2seq, Wfinb, bfin, (float*)d_out);
}